// Round 9
// baseline (324.275 us; speedup 1.0000x reference)
//
#include <hip/hip_runtime.h>
#include <hip/hip_bf16.h>

using short8 = __attribute__((ext_vector_type(8))) short;
using f32x4  = __attribute__((ext_vector_type(4))) float;

constexpr int Cdim = 64, Kcb = 1024, HWs = 4096;
constexpr int Npts = 131072;
constexpr int PTS  = 256;            // points per block (4 waves x 4 ptiles x 16)
constexpr float MARGIN = 0.02f;

// ws layout (bytes)
constexpr size_t WS_EH   = 0;        // [8][1024][8] bf16 hi planes
constexpr size_t WS_EL   = 131072;   // [8][1024][8] bf16 lo planes
constexpr size_t WS_EN   = 262144;   // f32[1024] exact norms
constexpr size_t WS_CNT  = 266240;   // u32 risky counter
constexpr size_t WS_LIST = 266304;   // u32[Npts] risky list
constexpr size_t WS_NEED = WS_LIST + 4 * (size_t)Npts;

// ---------- prep: split emb into bf16 hi/lo planes + exact f32 norms ----------
__global__ void vq_prep(const float* __restrict__ emb, unsigned short* __restrict__ eh,
                        unsigned short* __restrict__ el, float* __restrict__ en) {
  const int k = blockIdx.x * 256 + threadIdx.x;
  const float4* row = reinterpret_cast<const float4*>(emb + (k << 6));
  float a0 = 0.f, a1 = 0.f, a2 = 0.f, a3 = 0.f;
  #pragma unroll
  for (int cb = 0; cb < 8; ++cb) {
    float4 v0 = row[2 * cb], v1 = row[2 * cb + 1];
    float vv[8] = {v0.x, v0.y, v0.z, v0.w, v1.x, v1.y, v1.z, v1.w};
    short8 h8, l8;
    #pragma unroll
    for (int j = 0; j < 8; ++j) {
      const float x = vv[j];
      const unsigned short hs = __builtin_bit_cast(unsigned short, __float2bfloat16(x));
      const float hf = __builtin_bit_cast(float, (unsigned)hs << 16);
      const unsigned short ls = __builtin_bit_cast(unsigned short, __float2bfloat16(x - hf));
      h8[j] = (short)hs; l8[j] = (short)ls;
      if ((j & 3) == 0) a0 = fmaf(x, x, a0);
      if ((j & 3) == 1) a1 = fmaf(x, x, a1);
      if ((j & 3) == 2) a2 = fmaf(x, x, a2);
      if ((j & 3) == 3) a3 = fmaf(x, x, a3);
    }
    *reinterpret_cast<short8*>(&eh[((size_t)cb * Kcb + k) * 8]) = h8;
    *reinterpret_cast<short8*>(&el[((size_t)cb * Kcb + k) * 8]) = l8;
  }
  en[k] = (a0 + a1) + (a2 + a3);   // 4-acc order: matches vq_fix usage exactly
}

// ---------- main: MFMA approx scan, T14 issue-early staging, staged gather ----------
__global__ __launch_bounds__(256, 4) void vq_main(
    const float* __restrict__ ze, const float* __restrict__ emb,
    const unsigned short* __restrict__ eh, const unsigned short* __restrict__ el,
    const float* __restrict__ en, float* __restrict__ out,
    unsigned int* __restrict__ cnt, unsigned int* __restrict__ list, unsigned int listcap) {
  __shared__ unsigned short ebuf[2][8][128][8];   // 32 KB: [h/l][cblock][code][8]
  __shared__ __align__(16) float en_s[Kcb];       // 4 KB
  __shared__ int klds[PTS];                       // 1 KB winning index per point

  const int t = threadIdx.x;
  const int wave = t >> 6, lane = t & 63;
  const int g = lane >> 4, i16 = lane & 15;

  #pragma unroll
  for (int r = 0; r < 4; ++r) en_s[t + 256 * r] = en[t + 256 * r];

  // ---- B frags: this wave's 64 points (4 ptiles of 16); z_e loads nontemporal ----
  const int pbase = blockIdx.x * PTS + wave * 64;
  short8 Bh[4][2], Bl[4][2];
  #pragma unroll
  for (int p = 0; p < 4; ++p) {
    const int n = pbase + p * 16 + i16;
    const int b = n >> 12, hw = n & (HWs - 1);
    const float* xb = ze + (size_t)b * (Cdim * HWs) + hw;
    #pragma unroll
    for (int cs = 0; cs < 2; ++cs) {
      short8 fh, fl;
      #pragma unroll
      for (int j = 0; j < 8; ++j) {
        const int c = cs * 32 + g * 8 + j;
        const float x = __builtin_nontemporal_load(xb + c * HWs);
        const unsigned short hs = __builtin_bit_cast(unsigned short, __float2bfloat16(x));
        const float hf = __builtin_bit_cast(float, (unsigned)hs << 16);
        const unsigned short ls = __builtin_bit_cast(unsigned short, __float2bfloat16(x - hf));
        fh[j] = (short)hs; fl[j] = (short)ls;
      }
      Bh[p][cs] = fh; Bl[p][cs] = fl;
    }
  }

  float bd[4][4], bd2[4][4]; int bt[4][4];
  #pragma unroll
  for (int p = 0; p < 4; ++p)
    #pragma unroll
    for (int r = 0; r < 4; ++r) { bd[p][r] = 3.4e38f; bd2[p][r] = 3.4e38f; bt[p][r] = 0; }

  // ---- staging helpers (linear LDS image; reg-staged T14 split) ----
  float4 stg[8];
  // prologue: stage chunk 0
  #pragma unroll
  for (int q = 0; q < 8; ++q) {
    const int off16 = q * 256 + t;
    const int pp = off16 >> 7, inpiece = off16 & 127;
    const unsigned short* src = (pp < 8 ? eh : el) + (pp & 7) * (Kcb * 8) + inpiece * 8;
    stg[q] = *reinterpret_cast<const float4*>(src);
  }
  #pragma unroll
  for (int q = 0; q < 8; ++q) {
    const int off16 = q * 256 + t;
    *reinterpret_cast<float4*>(&reinterpret_cast<unsigned short*>(ebuf)[(size_t)off16 * 8]) = stg[q];
  }
  __syncthreads();

  #pragma unroll 1
  for (int cc = 0; cc < 8; ++cc) {
    // T14 issue-early: launch next chunk's global loads before compute
    if (cc < 7) {
      #pragma unroll
      for (int q = 0; q < 8; ++q) {
        const int off16 = q * 256 + t;
        const int pp = off16 >> 7, inpiece = off16 & 127;
        const unsigned short* src = (pp < 8 ? eh : el)
            + (pp & 7) * (Kcb * 8) + (cc + 1) * 1024 + inpiece * 8;
        stg[q] = *reinterpret_cast<const float4*>(src);
      }
    }

    for (int ct = 0; ct < 8; ++ct) {
      const int tile = cc * 8 + ct;
      const short8 Ah0 = *reinterpret_cast<const short8*>(&ebuf[0][0 + g][ct * 16 + i16][0]);
      const short8 Ah1 = *reinterpret_cast<const short8*>(&ebuf[0][4 + g][ct * 16 + i16][0]);
      const short8 Al0 = *reinterpret_cast<const short8*>(&ebuf[1][0 + g][ct * 16 + i16][0]);
      const short8 Al1 = *reinterpret_cast<const short8*>(&ebuf[1][4 + g][ct * 16 + i16][0]);
      const f32x4 enf = reinterpret_cast<const f32x4*>(en_s)[tile * 4 + g];
      f32x4 acc[4];
      #pragma unroll
      for (int p = 0; p < 4; ++p) { acc[p][0] = 0.f; acc[p][1] = 0.f; acc[p][2] = 0.f; acc[p][3] = 0.f; }
      // per-acc order identical to rounds 5/6: hh0, hh1, hl0, hl1, lh0, lh1
      #pragma unroll
      for (int p = 0; p < 4; ++p) acc[p] = __builtin_amdgcn_mfma_f32_16x16x32_bf16(Ah0, Bh[p][0], acc[p], 0, 0, 0);
      #pragma unroll
      for (int p = 0; p < 4; ++p) acc[p] = __builtin_amdgcn_mfma_f32_16x16x32_bf16(Ah1, Bh[p][1], acc[p], 0, 0, 0);
      #pragma unroll
      for (int p = 0; p < 4; ++p) acc[p] = __builtin_amdgcn_mfma_f32_16x16x32_bf16(Ah0, Bl[p][0], acc[p], 0, 0, 0);
      #pragma unroll
      for (int p = 0; p < 4; ++p) acc[p] = __builtin_amdgcn_mfma_f32_16x16x32_bf16(Ah1, Bl[p][1], acc[p], 0, 0, 0);
      #pragma unroll
      for (int p = 0; p < 4; ++p) acc[p] = __builtin_amdgcn_mfma_f32_16x16x32_bf16(Al0, Bh[p][0], acc[p], 0, 0, 0);
      #pragma unroll
      for (int p = 0; p < 4; ++p) acc[p] = __builtin_amdgcn_mfma_f32_16x16x32_bf16(Al1, Bh[p][1], acc[p], 0, 0, 0);
      #pragma unroll
      for (int p = 0; p < 4; ++p) {
        #pragma unroll
        for (int r = 0; r < 4; ++r) {
          const float d = fmaf(-2.0f, acc[p][r], enf[r]);
          const bool lt = d < bd[p][r];
          bd2[p][r] = fminf(bd2[p][r], fmaxf(d, bd[p][r]));
          bd[p][r]  = fminf(bd[p][r], d);
          bt[p][r]  = lt ? tile : bt[p][r];
        }
      }
    }
    __syncthreads();                 // all waves done reading ebuf
    if (cc < 7) {
      #pragma unroll
      for (int q = 0; q < 8; ++q) {  // write-late: commit prefetched chunk
        const int off16 = q * 256 + t;
        *reinterpret_cast<float4*>(&reinterpret_cast<unsigned short*>(ebuf)[(size_t)off16 * 8]) = stg[q];
      }
      __syncthreads();               // writes visible before next compute
    }
  }

  // ---- finalize per ptile: merge 4 reg-streams, then 4 lane-groups ----
  const unsigned long long lanebit = 1ull << lane;
  #pragma unroll
  for (int p = 0; p < 4; ++p) {
    float fb = bd[p][0];
    float f2 = bd2[p][0];
    int   fk = bt[p][0] * 16 + g * 4 + 0;
    #pragma unroll
    for (int r = 1; r < 4; ++r) {
      const float dr = bd[p][r];
      const int   kr = bt[p][r] * 16 + g * 4 + r;
      f2 = fminf(fminf(f2, bd2[p][r]), fmaxf(fb, dr));
      const bool take = dr < fb;   // cross-stream ties land inside MARGIN -> rescued
      fb = take ? dr : fb;
      fk = take ? kr : fk;
    }
    #pragma unroll
    for (int m = 16; m <= 32; m <<= 1) {
      const float od = __shfl_xor(fb, m, 64);
      const int   ok = __shfl_xor(fk, m, 64);
      const float o2 = __shfl_xor(f2, m, 64);
      f2 = fminf(fminf(f2, o2), fmaxf(fb, od));
      const bool take = (od < fb) || (od == fb && ok < fk);
      fb = take ? od : fb;
      fk = take ? ok : fk;
    }
    if (g == 0) klds[wave * 64 + p * 16 + i16] = fk;
    const bool risky = (g == 0) && (f2 - fb <= MARGIN);
    const unsigned long long msk = __ballot(risky);
    if (msk) {
      unsigned basev = 0;
      if (lane == 0) basev = atomicAdd(cnt, (unsigned)__popcll(msk));
      basev = (unsigned)__shfl((int)basev, 0, 64);
      if (risky) {
        const unsigned pos = basev + (unsigned)__popcll(msk & (lanebit - 1));
        if (pos < listcap) list[pos] = (unsigned)(pbase + p * 16 + i16);
      }
    }
  }
  __syncthreads();

  // ---- epilogue: thread t owns one point; full-wave 256B-contiguous stores ----
  const int np = blockIdx.x * PTS + t;
  const int kwin = klds[t];
  const float4* er = reinterpret_cast<const float4*>(emb + (kwin << 6));
  #pragma unroll
  for (int jj = 0; jj < 16; ++jj) {
    float4 v = er[jj];
    out[(size_t)(4 * jj + 0) * Npts + np] = v.x;
    out[(size_t)(4 * jj + 1) * Npts + np] = v.y;
    out[(size_t)(4 * jj + 2) * Npts + np] = v.z;
    out[(size_t)(4 * jj + 3) * Npts + np] = v.w;
  }
}

// ---------- fallback: exact arithmetic for risky points (1 wave/point, 4096 waves) ----------
__global__ __launch_bounds__(256) void vq_fix(
    const float* __restrict__ ze, const float* __restrict__ emb,
    const float* __restrict__ en, float* __restrict__ out,
    const unsigned int* __restrict__ cnt, const unsigned int* __restrict__ list,
    unsigned int listcap) {
  const int t = threadIdx.x;
  const int wave = t >> 6, lane = t & 63;
  unsigned count = *cnt;
  if (count > listcap) count = listcap;
  const unsigned wid = blockIdx.x * 4 + wave;
  for (unsigned i = wid; i < count; i += 4096) {
    const int n = (int)list[i];
    const int b = n >> 12, hw = n & (HWs - 1);
    const float* xp = ze + (size_t)b * (Cdim * HWs) + hw;
    float x[Cdim];
    #pragma unroll
    for (int c = 0; c < Cdim; ++c) x[c] = xp[c * HWs];
    float xn0 = 0.f, xn1 = 0.f, xn2 = 0.f, xn3 = 0.f;
    #pragma unroll
    for (int c = 0; c < Cdim; c += 4) {
      xn0 = fmaf(x[c], x[c], xn0);         xn1 = fmaf(x[c + 1], x[c + 1], xn1);
      xn2 = fmaf(x[c + 2], x[c + 2], xn2); xn3 = fmaf(x[c + 3], x[c + 3], xn3);
    }
    const float xnorm = (xn0 + xn1) + (xn2 + xn3);
    float best = 3.4e38f; int bestk = 0;
    for (int kk = 0; kk < 16; ++kk) {
      const int k = kk * 64 + lane;    // ascending within lane; coalesced en/emb reads
      const float4* er2 = reinterpret_cast<const float4*>(emb + (k << 6));
      float d0 = 0.f, d1 = 0.f, d2 = 0.f, d3 = 0.f;
      #pragma unroll
      for (int j = 0; j < 16; ++j) {
        float4 v = er2[j];
        d0 = fmaf(x[4 * j + 0], v.x, d0); d1 = fmaf(x[4 * j + 1], v.y, d1);
        d2 = fmaf(x[4 * j + 2], v.z, d2); d3 = fmaf(x[4 * j + 3], v.w, d3);
      }
      const float dot = (d0 + d1) + (d2 + d3);
      const float tt = xnorm + en[k];
      const float d = __fsub_rn(tt, __fmul_rn(2.0f, dot));
      if (d < best) { best = d; bestk = k; }
    }
    // lexicographic (d, k) wave reduce == global ascending-k first-min
    #pragma unroll
    for (int m = 1; m < 64; m <<= 1) {
      const float od = __shfl_xor(best, m, 64);
      const int   ok = __shfl_xor(bestk, m, 64);
      const bool take = (od < best) || (od == best && ok < bestk);
      best = take ? od : best;
      bestk = take ? ok : bestk;
    }
    out[(size_t)lane * Npts + n] = emb[(bestk << 6) + lane];
  }
}

// ---------- safety net (ws too small): round-4 proven kernel ----------
__global__ __launch_bounds__(256) void vq_direct(
    const float* __restrict__ ze, const float* __restrict__ emb, float* __restrict__ out) {
  __shared__ float en_s[Kcb];
  __shared__ float bestd_s[4][64];
  __shared__ int   bestk_s[4][64];
  const int t = threadIdx.x, wave = t >> 6, lane = t & 63;
  #pragma unroll
  for (int r = 0; r < 4; ++r) {
    const int k = t + r * 256;
    const float4* row = reinterpret_cast<const float4*>(emb + (k << 6));
    float a0 = 0.f, a1 = 0.f, a2 = 0.f, a3 = 0.f;
    #pragma unroll
    for (int j = 0; j < 16; ++j) {
      float4 v = row[j];
      a0 = fmaf(v.x, v.x, a0); a1 = fmaf(v.y, v.y, a1);
      a2 = fmaf(v.z, v.z, a2); a3 = fmaf(v.w, v.w, a3);
    }
    en_s[k] = (a0 + a1) + (a2 + a3);
  }
  __syncthreads();
  const int n = blockIdx.x * 64 + lane;
  const int b = n >> 12, hw = n & (HWs - 1);
  const float* xp = ze + (b * Cdim) * HWs + hw;
  float x[Cdim];
  #pragma unroll
  for (int c = 0; c < Cdim; ++c) x[c] = xp[c * HWs];
  float xn0 = 0.f, xn1 = 0.f, xn2 = 0.f, xn3 = 0.f;
  #pragma unroll
  for (int c = 0; c < Cdim; c += 4) {
    xn0 = fmaf(x[c], x[c], xn0); xn1 = fmaf(x[c + 1], x[c + 1], xn1);
    xn2 = fmaf(x[c + 2], x[c + 2], xn2); xn3 = fmaf(x[c + 3], x[c + 3], xn3);
  }
  const float xnorm = (xn0 + xn1) + (xn2 + xn3);
  const int wu = __builtin_amdgcn_readfirstlane(wave);
  const int kbase = wu * 256;
  float best = 3.4e38f; int bestk = 0;
  #pragma unroll 2
  for (int kk = 0; kk < 256; ++kk) {
    const int k = kbase + kk;
    const float4* er = reinterpret_cast<const float4*>(emb + (k << 6));
    float d0 = 0.f, d1 = 0.f, d2 = 0.f, d3 = 0.f;
    #pragma unroll
    for (int j = 0; j < 16; ++j) {
      float4 v = er[j];
      d0 = fmaf(x[4 * j + 0], v.x, d0); d1 = fmaf(x[4 * j + 1], v.y, d1);
      d2 = fmaf(x[4 * j + 2], v.z, d2); d3 = fmaf(x[4 * j + 3], v.w, d3);
    }
    const float dot = (d0 + d1) + (d2 + d3);
    const float tt = xnorm + en_s[k];
    const float d = __fsub_rn(tt, __fmul_rn(2.0f, dot));
    if (d < best) { best = d; bestk = k; }
  }
  bestd_s[wave][lane] = best; bestk_s[wave][lane] = bestk;
  __syncthreads();
  float bdv = bestd_s[0][lane]; int bkv = bestk_s[0][lane];
  #pragma unroll
  for (int w = 1; w < 4; ++w) {
    const float dw = bestd_s[w][lane]; const int kw = bestk_s[w][lane];
    if (dw < bdv) { bdv = dw; bkv = kw; }
  }
  const int np = blockIdx.x * 64 + lane;
  const int c0 = wave * 16;
  const float4* brow = reinterpret_cast<const float4*>(emb + (bkv << 6) + c0);
  #pragma unroll
  for (int j = 0; j < 4; ++j) {
    float4 v = brow[j];
    out[(c0 + 4 * j + 0) * Npts + np] = v.x;
    out[(c0 + 4 * j + 1) * Npts + np] = v.y;
    out[(c0 + 4 * j + 2) * Npts + np] = v.z;
    out[(c0 + 4 * j + 3) * Npts + np] = v.w;
  }
}

extern "C" void kernel_launch(void* const* d_in, const int* in_sizes, int n_in,
                              void* d_out, int out_size, void* d_ws, size_t ws_size,
                              hipStream_t stream) {
  (void)in_sizes; (void)n_in; (void)out_size;
  const float* ze  = (const float*)d_in[0];
  const float* emb = (const float*)d_in[1];
  float* out = (float*)d_out;

  if (ws_size < WS_NEED) {   // safety net: proven round-4 path
    vq_direct<<<Npts / 64, 256, 0, stream>>>(ze, emb, out);
    return;
  }
  unsigned char* ws = (unsigned char*)d_ws;
  unsigned short* eh = (unsigned short*)(ws + WS_EH);
  unsigned short* el = (unsigned short*)(ws + WS_EL);
  float* en          = (float*)(ws + WS_EN);
  unsigned* cnt      = (unsigned*)(ws + WS_CNT);
  unsigned* list     = (unsigned*)(ws + WS_LIST);

  hipMemsetAsync(cnt, 0, 4, stream);
  vq_prep<<<Kcb / 256, 256, 0, stream>>>(emb, eh, el, en);
  vq_main<<<Npts / PTS, 256, 0, stream>>>(ze, emb, eh, el, en, out, cnt, list, (unsigned)Npts);
  vq_fix<<<1024, 256, 0, stream>>>(ze, emb, en, out, cnt, list, (unsigned)Npts);
}

// Round 10
// 286.647 us; speedup vs baseline: 1.1313x; 1.1313x over previous
//
#include <hip/hip_runtime.h>
#include <hip/hip_bf16.h>

using short8 = __attribute__((ext_vector_type(8))) short;
using f32x4  = __attribute__((ext_vector_type(4))) float;

constexpr int Cdim = 64, Kcb = 1024, HWs = 4096;
constexpr int Npts = 131072;
constexpr int PTS  = 256;            // points per block (8 waves x 2 ptiles x 16)
constexpr float MARGIN = 0.006f;     // ~4.6x the 3-plane approx error bound (~1.3e-3)

// ws layout (bytes)
constexpr size_t WS_EH   = 0;        // [8][1024][8] bf16 hi planes
constexpr size_t WS_EL   = 131072;   // [8][1024][8] bf16 lo planes
constexpr size_t WS_EN   = 262144;   // f32[1024] exact norms
constexpr size_t WS_CNT  = 266240;   // u32 risky counter
constexpr size_t WS_LIST = 266304;   // u32[Npts] risky list
constexpr size_t WS_NEED = WS_LIST + 4 * (size_t)Npts;

// ---------- prep: split emb into bf16 hi/lo planes + exact f32 norms ----------
__global__ void vq_prep(const float* __restrict__ emb, unsigned short* __restrict__ eh,
                        unsigned short* __restrict__ el, float* __restrict__ en) {
  const int k = blockIdx.x * 256 + threadIdx.x;
  const float4* row = reinterpret_cast<const float4*>(emb + (k << 6));
  float a0 = 0.f, a1 = 0.f, a2 = 0.f, a3 = 0.f;
  #pragma unroll
  for (int cb = 0; cb < 8; ++cb) {
    float4 v0 = row[2 * cb], v1 = row[2 * cb + 1];
    float vv[8] = {v0.x, v0.y, v0.z, v0.w, v1.x, v1.y, v1.z, v1.w};
    short8 h8, l8;
    #pragma unroll
    for (int j = 0; j < 8; ++j) {
      const float x = vv[j];
      const unsigned short hs = __builtin_bit_cast(unsigned short, __float2bfloat16(x));
      const float hf = __builtin_bit_cast(float, (unsigned)hs << 16);
      const unsigned short ls = __builtin_bit_cast(unsigned short, __float2bfloat16(x - hf));
      h8[j] = (short)hs; l8[j] = (short)ls;
      if ((j & 3) == 0) a0 = fmaf(x, x, a0);
      if ((j & 3) == 1) a1 = fmaf(x, x, a1);
      if ((j & 3) == 2) a2 = fmaf(x, x, a2);
      if ((j & 3) == 3) a3 = fmaf(x, x, a3);
    }
    *reinterpret_cast<short8*>(&eh[((size_t)cb * Kcb + k) * 8]) = h8;
    *reinterpret_cast<short8*>(&el[((size_t)cb * Kcb + k) * 8]) = l8;
  }
  en[k] = (a0 + a1) + (a2 + a3);   // 4-acc order: matches vq_fix usage exactly
}

// ---------- main: MFMA approx scan; 8 waves x 2 ptiles => ~110 VGPR, no spill ----------
__global__ __launch_bounds__(512, 4) void vq_main(
    const float* __restrict__ ze, const float* __restrict__ emb,
    const unsigned short* __restrict__ eh, const unsigned short* __restrict__ el,
    const float* __restrict__ en, float* __restrict__ out,
    unsigned int* __restrict__ cnt, unsigned int* __restrict__ list, unsigned int listcap) {
  __shared__ unsigned short ebuf[2][8][128][8];   // 32 KB: [h/l][cblock][code][8]
  __shared__ __align__(16) float en_s[Kcb];       // 4 KB
  __shared__ int klds[PTS];                       // 1 KB winning index per point

  const int t = threadIdx.x;
  const int wave = t >> 6, lane = t & 63;
  const int g = lane >> 4, i16 = lane & 15;

  en_s[t] = en[t];
  en_s[t + 512] = en[t + 512];

  // ---- B frags: this wave's 32 points (2 ptiles of 16); z_e loads nontemporal ----
  const int pbase = blockIdx.x * PTS + wave * 32;
  short8 Bh[2][2], Bl[2][2];
  #pragma unroll
  for (int p = 0; p < 2; ++p) {
    const int n = pbase + p * 16 + i16;
    const int b = n >> 12, hw = n & (HWs - 1);
    const float* xb = ze + (size_t)b * (Cdim * HWs) + hw;
    #pragma unroll
    for (int cs = 0; cs < 2; ++cs) {
      short8 fh, fl;
      #pragma unroll
      for (int j = 0; j < 8; ++j) {
        const int c = cs * 32 + g * 8 + j;
        const float x = __builtin_nontemporal_load(xb + c * HWs);
        const unsigned short hs = __builtin_bit_cast(unsigned short, __float2bfloat16(x));
        const float hf = __builtin_bit_cast(float, (unsigned)hs << 16);
        const unsigned short ls = __builtin_bit_cast(unsigned short, __float2bfloat16(x - hf));
        fh[j] = (short)hs; fl[j] = (short)ls;
      }
      Bh[p][cs] = fh; Bl[p][cs] = fl;
    }
  }

  float bd[2][4], bd2[2][4]; int bt[2][4];
  #pragma unroll
  for (int p = 0; p < 2; ++p)
    #pragma unroll
    for (int r = 0; r < 4; ++r) { bd[p][r] = 3.4e38f; bd2[p][r] = 3.4e38f; bt[p][r] = 0; }

  // ---- staging: 512 threads x 4 float4 = 32 KB chunk image (linear) ----
  float4 stg[4];
  #pragma unroll
  for (int q = 0; q < 4; ++q) {       // prologue: chunk 0
    const int off16 = q * 512 + t;
    const int pp = off16 >> 7, inpiece = off16 & 127;
    const unsigned short* src = (pp < 8 ? eh : el) + (pp & 7) * (Kcb * 8) + inpiece * 8;
    stg[q] = *reinterpret_cast<const float4*>(src);
  }
  #pragma unroll
  for (int q = 0; q < 4; ++q) {
    const int off16 = q * 512 + t;
    *reinterpret_cast<float4*>(&reinterpret_cast<unsigned short*>(ebuf)[(size_t)off16 * 8]) = stg[q];
  }
  __syncthreads();

  #pragma unroll 1
  for (int cc = 0; cc < 8; ++cc) {
    // T14 issue-early: next chunk's global loads in flight across the compute
    if (cc < 7) {
      #pragma unroll
      for (int q = 0; q < 4; ++q) {
        const int off16 = q * 512 + t;
        const int pp = off16 >> 7, inpiece = off16 & 127;
        const unsigned short* src = (pp < 8 ? eh : el)
            + (pp & 7) * (Kcb * 8) + (cc + 1) * 1024 + inpiece * 8;
        stg[q] = *reinterpret_cast<const float4*>(src);
      }
    }

    for (int ct = 0; ct < 8; ++ct) {
      const int tile = cc * 8 + ct;
      const short8 Ah0 = *reinterpret_cast<const short8*>(&ebuf[0][0 + g][ct * 16 + i16][0]);
      const short8 Ah1 = *reinterpret_cast<const short8*>(&ebuf[0][4 + g][ct * 16 + i16][0]);
      const short8 Al0 = *reinterpret_cast<const short8*>(&ebuf[1][0 + g][ct * 16 + i16][0]);
      const short8 Al1 = *reinterpret_cast<const short8*>(&ebuf[1][4 + g][ct * 16 + i16][0]);
      const f32x4 enf = reinterpret_cast<const f32x4*>(en_s)[tile * 4 + g];
      f32x4 acc[2];
      #pragma unroll
      for (int p = 0; p < 2; ++p) { acc[p][0] = 0.f; acc[p][1] = 0.f; acc[p][2] = 0.f; acc[p][3] = 0.f; }
      // per-acc order identical to rounds 5/6/9: hh0, hh1, hl0, hl1, lh0, lh1
      #pragma unroll
      for (int p = 0; p < 2; ++p) acc[p] = __builtin_amdgcn_mfma_f32_16x16x32_bf16(Ah0, Bh[p][0], acc[p], 0, 0, 0);
      #pragma unroll
      for (int p = 0; p < 2; ++p) acc[p] = __builtin_amdgcn_mfma_f32_16x16x32_bf16(Ah1, Bh[p][1], acc[p], 0, 0, 0);
      #pragma unroll
      for (int p = 0; p < 2; ++p) acc[p] = __builtin_amdgcn_mfma_f32_16x16x32_bf16(Ah0, Bl[p][0], acc[p], 0, 0, 0);
      #pragma unroll
      for (int p = 0; p < 2; ++p) acc[p] = __builtin_amdgcn_mfma_f32_16x16x32_bf16(Ah1, Bl[p][1], acc[p], 0, 0, 0);
      #pragma unroll
      for (int p = 0; p < 2; ++p) acc[p] = __builtin_amdgcn_mfma_f32_16x16x32_bf16(Al0, Bh[p][0], acc[p], 0, 0, 0);
      #pragma unroll
      for (int p = 0; p < 2; ++p) acc[p] = __builtin_amdgcn_mfma_f32_16x16x32_bf16(Al1, Bh[p][1], acc[p], 0, 0, 0);
      #pragma unroll
      for (int p = 0; p < 2; ++p) {
        #pragma unroll
        for (int r = 0; r < 4; ++r) {
          const float d = fmaf(-2.0f, acc[p][r], enf[r]);
          const bool lt = d < bd[p][r];
          bd2[p][r] = fminf(bd2[p][r], fmaxf(d, bd[p][r]));
          bd[p][r]  = fminf(bd[p][r], d);
          bt[p][r]  = lt ? tile : bt[p][r];
        }
      }
    }
    __syncthreads();                 // all waves done reading ebuf
    if (cc < 7) {
      #pragma unroll
      for (int q = 0; q < 4; ++q) {  // write-late: commit prefetched chunk
        const int off16 = q * 512 + t;
        *reinterpret_cast<float4*>(&reinterpret_cast<unsigned short*>(ebuf)[(size_t)off16 * 8]) = stg[q];
      }
      __syncthreads();               // writes visible before next compute
    }
  }

  // ---- finalize per ptile: merge 4 reg-streams, then 4 lane-groups ----
  const unsigned long long lanebit = 1ull << lane;
  #pragma unroll
  for (int p = 0; p < 2; ++p) {
    float fb = bd[p][0];
    float f2 = bd2[p][0];
    int   fk = bt[p][0] * 16 + g * 4 + 0;
    #pragma unroll
    for (int r = 1; r < 4; ++r) {
      const float dr = bd[p][r];
      const int   kr = bt[p][r] * 16 + g * 4 + r;
      f2 = fminf(fminf(f2, bd2[p][r]), fmaxf(fb, dr));
      const bool take = dr < fb;   // cross-stream ties land inside MARGIN -> rescued
      fb = take ? dr : fb;
      fk = take ? kr : fk;
    }
    #pragma unroll
    for (int m = 16; m <= 32; m <<= 1) {
      const float od = __shfl_xor(fb, m, 64);
      const int   ok = __shfl_xor(fk, m, 64);
      const float o2 = __shfl_xor(f2, m, 64);
      f2 = fminf(fminf(f2, o2), fmaxf(fb, od));
      const bool take = (od < fb) || (od == fb && ok < fk);
      fb = take ? od : fb;
      fk = take ? ok : fk;
    }
    if (g == 0) klds[wave * 32 + p * 16 + i16] = fk;
    const bool risky = (g == 0) && (f2 - fb <= MARGIN);
    const unsigned long long msk = __ballot(risky);
    if (msk) {
      unsigned basev = 0;
      if (lane == 0) basev = atomicAdd(cnt, (unsigned)__popcll(msk));
      basev = (unsigned)__shfl((int)basev, 0, 64);
      if (risky) {
        const unsigned pos = basev + (unsigned)__popcll(msk & (lanebit - 1));
        if (pos < listcap) list[pos] = (unsigned)(pbase + p * 16 + i16);
      }
    }
  }
  __syncthreads();

  // ---- epilogue: thread t -> point (t&255), channels [(t>>8)*32, +32);
  // full-wave 256B-contiguous NONTEMPORAL stores (keep codebook L2-resident) ----
  const int np = blockIdx.x * PTS + (t & 255);
  const int c0 = (t >> 8) * 32;
  const int kwin = klds[t & 255];
  const float4* er = reinterpret_cast<const float4*>(emb + (kwin << 6) + c0);
  #pragma unroll
  for (int jj = 0; jj < 8; ++jj) {
    float4 v = er[jj];
    __builtin_nontemporal_store(v.x, &out[(size_t)(c0 + 4 * jj + 0) * Npts + np]);
    __builtin_nontemporal_store(v.y, &out[(size_t)(c0 + 4 * jj + 1) * Npts + np]);
    __builtin_nontemporal_store(v.z, &out[(size_t)(c0 + 4 * jj + 2) * Npts + np]);
    __builtin_nontemporal_store(v.w, &out[(size_t)(c0 + 4 * jj + 3) * Npts + np]);
  }
}

// ---------- fallback: exact arithmetic for risky points (1 wave/point, 4096 waves) ----------
__global__ __launch_bounds__(256) void vq_fix(
    const float* __restrict__ ze, const float* __restrict__ emb,
    const float* __restrict__ en, float* __restrict__ out,
    const unsigned int* __restrict__ cnt, const unsigned int* __restrict__ list,
    unsigned int listcap) {
  const int t = threadIdx.x;
  const int wave = t >> 6, lane = t & 63;
  unsigned count = *cnt;
  if (count > listcap) count = listcap;
  const unsigned wid = blockIdx.x * 4 + wave;
  for (unsigned i = wid; i < count; i += 4096) {
    const int n = (int)list[i];
    const int b = n >> 12, hw = n & (HWs - 1);
    const float* xp = ze + (size_t)b * (Cdim * HWs) + hw;
    float x[Cdim];
    #pragma unroll
    for (int c = 0; c < Cdim; ++c) x[c] = xp[c * HWs];
    float xn0 = 0.f, xn1 = 0.f, xn2 = 0.f, xn3 = 0.f;
    #pragma unroll
    for (int c = 0; c < Cdim; c += 4) {
      xn0 = fmaf(x[c], x[c], xn0);         xn1 = fmaf(x[c + 1], x[c + 1], xn1);
      xn2 = fmaf(x[c + 2], x[c + 2], xn2); xn3 = fmaf(x[c + 3], x[c + 3], xn3);
    }
    const float xnorm = (xn0 + xn1) + (xn2 + xn3);
    float best = 3.4e38f; int bestk = 0;
    for (int kk = 0; kk < 16; ++kk) {
      const int k = kk * 64 + lane;    // ascending within lane; coalesced en/emb reads
      const float4* er2 = reinterpret_cast<const float4*>(emb + (k << 6));
      float d0 = 0.f, d1 = 0.f, d2 = 0.f, d3 = 0.f;
      #pragma unroll
      for (int j = 0; j < 16; ++j) {
        float4 v = er2[j];
        d0 = fmaf(x[4 * j + 0], v.x, d0); d1 = fmaf(x[4 * j + 1], v.y, d1);
        d2 = fmaf(x[4 * j + 2], v.z, d2); d3 = fmaf(x[4 * j + 3], v.w, d3);
      }
      const float dot = (d0 + d1) + (d2 + d3);
      const float tt = xnorm + en[k];
      const float d = __fsub_rn(tt, __fmul_rn(2.0f, dot));
      if (d < best) { best = d; bestk = k; }
    }
    // lexicographic (d, k) wave reduce == global ascending-k first-min
    #pragma unroll
    for (int m = 1; m < 64; m <<= 1) {
      const float od = __shfl_xor(best, m, 64);
      const int   ok = __shfl_xor(bestk, m, 64);
      const bool take = (od < best) || (od == best && ok < bestk);
      best = take ? od : best;
      bestk = take ? ok : bestk;
    }
    out[(size_t)lane * Npts + n] = emb[(bestk << 6) + lane];
  }
}

// ---------- safety net (ws too small): round-4 proven kernel ----------
__global__ __launch_bounds__(256) void vq_direct(
    const float* __restrict__ ze, const float* __restrict__ emb, float* __restrict__ out) {
  __shared__ float en_s[Kcb];
  __shared__ float bestd_s[4][64];
  __shared__ int   bestk_s[4][64];
  const int t = threadIdx.x, wave = t >> 6, lane = t & 63;
  #pragma unroll
  for (int r = 0; r < 4; ++r) {
    const int k = t + r * 256;
    const float4* row = reinterpret_cast<const float4*>(emb + (k << 6));
    float a0 = 0.f, a1 = 0.f, a2 = 0.f, a3 = 0.f;
    #pragma unroll
    for (int j = 0; j < 16; ++j) {
      float4 v = row[j];
      a0 = fmaf(v.x, v.x, a0); a1 = fmaf(v.y, v.y, a1);
      a2 = fmaf(v.z, v.z, a2); a3 = fmaf(v.w, v.w, a3);
    }
    en_s[k] = (a0 + a1) + (a2 + a3);
  }
  __syncthreads();
  const int n = blockIdx.x * 64 + lane;
  const int b = n >> 12, hw = n & (HWs - 1);
  const float* xp = ze + (b * Cdim) * HWs + hw;
  float x[Cdim];
  #pragma unroll
  for (int c = 0; c < Cdim; ++c) x[c] = xp[c * HWs];
  float xn0 = 0.f, xn1 = 0.f, xn2 = 0.f, xn3 = 0.f;
  #pragma unroll
  for (int c = 0; c < Cdim; c += 4) {
    xn0 = fmaf(x[c], x[c], xn0); xn1 = fmaf(x[c + 1], x[c + 1], xn1);
    xn2 = fmaf(x[c + 2], x[c + 2], xn2); xn3 = fmaf(x[c + 3], x[c + 3], xn3);
  }
  const float xnorm = (xn0 + xn1) + (xn2 + xn3);
  const int wu = __builtin_amdgcn_readfirstlane(wave);
  const int kbase = wu * 256;
  float best = 3.4e38f; int bestk = 0;
  #pragma unroll 2
  for (int kk = 0; kk < 256; ++kk) {
    const int k = kbase + kk;
    const float4* er = reinterpret_cast<const float4*>(emb + (k << 6));
    float d0 = 0.f, d1 = 0.f, d2 = 0.f, d3 = 0.f;
    #pragma unroll
    for (int j = 0; j < 16; ++j) {
      float4 v = er[j];
      d0 = fmaf(x[4 * j + 0], v.x, d0); d1 = fmaf(x[4 * j + 1], v.y, d1);
      d2 = fmaf(x[4 * j + 2], v.z, d2); d3 = fmaf(x[4 * j + 3], v.w, d3);
    }
    const float dot = (d0 + d1) + (d2 + d3);
    const float tt = xnorm + en_s[k];
    const float d = __fsub_rn(tt, __fmul_rn(2.0f, dot));
    if (d < best) { best = d; bestk = k; }
  }
  bestd_s[wave][lane] = best; bestk_s[wave][lane] = bestk;
  __syncthreads();
  float bdv = bestd_s[0][lane]; int bkv = bestk_s[0][lane];
  #pragma unroll
  for (int w = 1; w < 4; ++w) {
    const float dw = bestd_s[w][lane]; const int kw = bestk_s[w][lane];
    if (dw < bdv) { bdv = dw; bkv = kw; }
  }
  const int np = blockIdx.x * 64 + lane;
  const int c0 = wave * 16;
  const float4* brow = reinterpret_cast<const float4*>(emb + (bkv << 6) + c0);
  #pragma unroll
  for (int j = 0; j < 4; ++j) {
    float4 v = brow[j];
    out[(c0 + 4 * j + 0) * Npts + np] = v.x;
    out[(c0 + 4 * j + 1) * Npts + np] = v.y;
    out[(c0 + 4 * j + 2) * Npts + np] = v.z;
    out[(c0 + 4 * j + 3) * Npts + np] = v.w;
  }
}

extern "C" void kernel_launch(void* const* d_in, const int* in_sizes, int n_in,
                              void* d_out, int out_size, void* d_ws, size_t ws_size,
                              hipStream_t stream) {
  (void)in_sizes; (void)n_in; (void)out_size;
  const float* ze  = (const float*)d_in[0];
  const float* emb = (const float*)d_in[1];
  float* out = (float*)d_out;

  if (ws_size < WS_NEED) {   // safety net: proven round-4 path
    vq_direct<<<Npts / 64, 256, 0, stream>>>(ze, emb, out);
    return;
  }
  unsigned char* ws = (unsigned char*)d_ws;
  unsigned short* eh = (unsigned short*)(ws + WS_EH);
  unsigned short* el = (unsigned short*)(ws + WS_EL);
  float* en          = (float*)(ws + WS_EN);
  unsigned* cnt      = (unsigned*)(ws + WS_CNT);
  unsigned* list     = (unsigned*)(ws + WS_LIST);

  hipMemsetAsync(cnt, 0, 4, stream);
  vq_prep<<<Kcb / 256, 256, 0, stream>>>(emb, eh, el, en);
  vq_main<<<Npts / PTS, 512, 0, stream>>>(ze, emb, eh, el, en, out, cnt, list, (unsigned)Npts);
  vq_fix<<<1024, 256, 0, stream>>>(ze, emb, en, out, cnt, list, (unsigned)Npts);
}

// Round 11
// 215.433 us; speedup vs baseline: 1.5052x; 1.3306x over previous
//
#include <hip/hip_runtime.h>
#include <hip/hip_bf16.h>

using short8 = __attribute__((ext_vector_type(8))) short;
using f32x4  = __attribute__((ext_vector_type(4))) float;

constexpr int Cdim = 64, Kcb = 1024, HWs = 4096;
constexpr int Npts = 131072;
constexpr int PTS  = 256;            // points per block (4 waves x 4 ptiles x 16)
constexpr float MARGIN = 0.02f;      // round-5/6-proven rescue margin

// ws layout (bytes)
constexpr size_t WS_EH   = 0;        // [8][1024][8] bf16 hi planes
constexpr size_t WS_EL   = 131072;   // [8][1024][8] bf16 lo planes
constexpr size_t WS_EN   = 262144;   // f32[1024] exact norms
constexpr size_t WS_CNT  = 266240;   // u32 risky counter
constexpr size_t WS_LIST = 266304;   // u32[Npts] risky list
constexpr size_t WS_NEED = WS_LIST + 4 * (size_t)Npts;

// ---------- prep: split emb into bf16 hi/lo planes + exact f32 norms ----------
__global__ void vq_prep(const float* __restrict__ emb, unsigned short* __restrict__ eh,
                        unsigned short* __restrict__ el, float* __restrict__ en) {
  const int k = blockIdx.x * 256 + threadIdx.x;
  const float4* row = reinterpret_cast<const float4*>(emb + (k << 6));
  float a0 = 0.f, a1 = 0.f, a2 = 0.f, a3 = 0.f;
  #pragma unroll
  for (int cb = 0; cb < 8; ++cb) {
    float4 v0 = row[2 * cb], v1 = row[2 * cb + 1];
    float vv[8] = {v0.x, v0.y, v0.z, v0.w, v1.x, v1.y, v1.z, v1.w};
    short8 h8, l8;
    #pragma unroll
    for (int j = 0; j < 8; ++j) {
      const float x = vv[j];
      const unsigned short hs = __builtin_bit_cast(unsigned short, __float2bfloat16(x));
      const float hf = __builtin_bit_cast(float, (unsigned)hs << 16);
      const unsigned short ls = __builtin_bit_cast(unsigned short, __float2bfloat16(x - hf));
      h8[j] = (short)hs; l8[j] = (short)ls;
      if ((j & 3) == 0) a0 = fmaf(x, x, a0);
      if ((j & 3) == 1) a1 = fmaf(x, x, a1);
      if ((j & 3) == 2) a2 = fmaf(x, x, a2);
      if ((j & 3) == 3) a3 = fmaf(x, x, a3);
    }
    *reinterpret_cast<short8*>(&eh[((size_t)cb * Kcb + k) * 8]) = h8;
    *reinterpret_cast<short8*>(&el[((size_t)cb * Kcb + k) * 8]) = l8;
  }
  en[k] = (a0 + a1) + (a2 + a3);   // 4-acc order: matches vq_fix usage exactly
}

// ---------- main: MFMA approx scan; (256,2) = 256-reg cap -> NO SPILL ----------
__global__ __launch_bounds__(256, 2) void vq_main(
    const float* __restrict__ ze, const float* __restrict__ emb,
    const unsigned short* __restrict__ eh, const unsigned short* __restrict__ el,
    const float* __restrict__ en, float* __restrict__ out,
    unsigned int* __restrict__ cnt, unsigned int* __restrict__ list, unsigned int listcap) {
  __shared__ unsigned short ebuf[2][8][128][8];   // 32 KB: [h/l][cblock][code][8]
  __shared__ __align__(16) float en_s[Kcb];       // 4 KB
  __shared__ int klds[PTS];                       // 1 KB winning index per point

  const int t = threadIdx.x;
  const int wave = t >> 6, lane = t & 63;
  const int g = lane >> 4, i16 = lane & 15;

  #pragma unroll
  for (int r = 0; r < 4; ++r) en_s[t + 256 * r] = en[t + 256 * r];

  // ---- B frags: this wave's 64 points (4 ptiles of 16); z_e loads nontemporal ----
  const int pbase = blockIdx.x * PTS + wave * 64;
  short8 Bh[4][2], Bl[4][2];
  #pragma unroll
  for (int p = 0; p < 4; ++p) {
    const int n = pbase + p * 16 + i16;
    const int b = n >> 12, hw = n & (HWs - 1);
    const float* xb = ze + (size_t)b * (Cdim * HWs) + hw;
    #pragma unroll
    for (int cs = 0; cs < 2; ++cs) {
      short8 fh, fl;
      #pragma unroll
      for (int j = 0; j < 8; ++j) {
        const int c = cs * 32 + g * 8 + j;
        const float x = __builtin_nontemporal_load(xb + c * HWs);
        const unsigned short hs = __builtin_bit_cast(unsigned short, __float2bfloat16(x));
        const float hf = __builtin_bit_cast(float, (unsigned)hs << 16);
        const unsigned short ls = __builtin_bit_cast(unsigned short, __float2bfloat16(x - hf));
        fh[j] = (short)hs; fl[j] = (short)ls;
      }
      Bh[p][cs] = fh; Bl[p][cs] = fl;
    }
  }

  float bd[4][4], bd2[4][4]; int bt[4][4];
  #pragma unroll
  for (int p = 0; p < 4; ++p)
    #pragma unroll
    for (int r = 0; r < 4; ++r) { bd[p][r] = 3.4e38f; bd2[p][r] = 3.4e38f; bt[p][r] = 0; }

  // ---- T14 reg-staged double-buffer of the 32 KB chunk image ----
  float4 stg[8];
  #pragma unroll
  for (int q = 0; q < 8; ++q) {       // prologue: chunk 0
    const int off16 = q * 256 + t;
    const int pp = off16 >> 7, inpiece = off16 & 127;
    const unsigned short* src = (pp < 8 ? eh : el) + (pp & 7) * (Kcb * 8) + inpiece * 8;
    stg[q] = *reinterpret_cast<const float4*>(src);
  }
  #pragma unroll
  for (int q = 0; q < 8; ++q) {
    const int off16 = q * 256 + t;
    *reinterpret_cast<float4*>(&reinterpret_cast<unsigned short*>(ebuf)[(size_t)off16 * 8]) = stg[q];
  }
  __syncthreads();

  #pragma unroll 1
  for (int cc = 0; cc < 8; ++cc) {
    // T14 issue-early: next chunk's global loads in flight across the compute
    if (cc < 7) {
      #pragma unroll
      for (int q = 0; q < 8; ++q) {
        const int off16 = q * 256 + t;
        const int pp = off16 >> 7, inpiece = off16 & 127;
        const unsigned short* src = (pp < 8 ? eh : el)
            + (pp & 7) * (Kcb * 8) + (cc + 1) * 1024 + inpiece * 8;
        stg[q] = *reinterpret_cast<const float4*>(src);
      }
    }

    for (int ct = 0; ct < 8; ++ct) {
      const int tile = cc * 8 + ct;
      const short8 Ah0 = *reinterpret_cast<const short8*>(&ebuf[0][0 + g][ct * 16 + i16][0]);
      const short8 Ah1 = *reinterpret_cast<const short8*>(&ebuf[0][4 + g][ct * 16 + i16][0]);
      const short8 Al0 = *reinterpret_cast<const short8*>(&ebuf[1][0 + g][ct * 16 + i16][0]);
      const short8 Al1 = *reinterpret_cast<const short8*>(&ebuf[1][4 + g][ct * 16 + i16][0]);
      const f32x4 enf = reinterpret_cast<const f32x4*>(en_s)[tile * 4 + g];
      f32x4 acc[4];
      #pragma unroll
      for (int p = 0; p < 4; ++p) { acc[p][0] = 0.f; acc[p][1] = 0.f; acc[p][2] = 0.f; acc[p][3] = 0.f; }
      // per-acc order identical to rounds 5/6/9/10: hh0, hh1, hl0, hl1, lh0, lh1
      #pragma unroll
      for (int p = 0; p < 4; ++p) acc[p] = __builtin_amdgcn_mfma_f32_16x16x32_bf16(Ah0, Bh[p][0], acc[p], 0, 0, 0);
      #pragma unroll
      for (int p = 0; p < 4; ++p) acc[p] = __builtin_amdgcn_mfma_f32_16x16x32_bf16(Ah1, Bh[p][1], acc[p], 0, 0, 0);
      #pragma unroll
      for (int p = 0; p < 4; ++p) acc[p] = __builtin_amdgcn_mfma_f32_16x16x32_bf16(Ah0, Bl[p][0], acc[p], 0, 0, 0);
      #pragma unroll
      for (int p = 0; p < 4; ++p) acc[p] = __builtin_amdgcn_mfma_f32_16x16x32_bf16(Ah1, Bl[p][1], acc[p], 0, 0, 0);
      #pragma unroll
      for (int p = 0; p < 4; ++p) acc[p] = __builtin_amdgcn_mfma_f32_16x16x32_bf16(Al0, Bh[p][0], acc[p], 0, 0, 0);
      #pragma unroll
      for (int p = 0; p < 4; ++p) acc[p] = __builtin_amdgcn_mfma_f32_16x16x32_bf16(Al1, Bh[p][1], acc[p], 0, 0, 0);
      #pragma unroll
      for (int p = 0; p < 4; ++p) {
        #pragma unroll
        for (int r = 0; r < 4; ++r) {
          const float d = fmaf(-2.0f, acc[p][r], enf[r]);
          const bool lt = d < bd[p][r];
          bd2[p][r] = fminf(bd2[p][r], fmaxf(d, bd[p][r]));
          bd[p][r]  = fminf(bd[p][r], d);
          bt[p][r]  = lt ? tile : bt[p][r];
        }
      }
    }
    __syncthreads();                 // all waves done reading ebuf
    if (cc < 7) {
      #pragma unroll
      for (int q = 0; q < 8; ++q) {  // write-late: commit prefetched chunk
        const int off16 = q * 256 + t;
        *reinterpret_cast<float4*>(&reinterpret_cast<unsigned short*>(ebuf)[(size_t)off16 * 8]) = stg[q];
      }
      __syncthreads();               // writes visible before next compute
    }
  }

  // ---- finalize per ptile: merge 4 reg-streams, then 4 lane-groups ----
  const unsigned long long lanebit = 1ull << lane;
  #pragma unroll
  for (int p = 0; p < 4; ++p) {
    float fb = bd[p][0];
    float f2 = bd2[p][0];
    int   fk = bt[p][0] * 16 + g * 4 + 0;
    #pragma unroll
    for (int r = 1; r < 4; ++r) {
      const float dr = bd[p][r];
      const int   kr = bt[p][r] * 16 + g * 4 + r;
      f2 = fminf(fminf(f2, bd2[p][r]), fmaxf(fb, dr));
      const bool take = dr < fb;   // cross-stream ties land inside MARGIN -> rescued
      fb = take ? dr : fb;
      fk = take ? kr : fk;
    }
    #pragma unroll
    for (int m = 16; m <= 32; m <<= 1) {
      const float od = __shfl_xor(fb, m, 64);
      const int   ok = __shfl_xor(fk, m, 64);
      const float o2 = __shfl_xor(f2, m, 64);
      f2 = fminf(fminf(f2, o2), fmaxf(fb, od));
      const bool take = (od < fb) || (od == fb && ok < fk);
      fb = take ? od : fb;
      fk = take ? ok : fk;
    }
    if (g == 0) klds[wave * 64 + p * 16 + i16] = fk;
    const bool risky = (g == 0) && (f2 - fb <= MARGIN);
    const unsigned long long msk = __ballot(risky);
    if (msk) {
      unsigned basev = 0;
      if (lane == 0) basev = atomicAdd(cnt, (unsigned)__popcll(msk));
      basev = (unsigned)__shfl((int)basev, 0, 64);
      if (risky) {
        const unsigned pos = basev + (unsigned)__popcll(msk & (lanebit - 1));
        if (pos < listcap) list[pos] = (unsigned)(pbase + p * 16 + i16);
      }
    }
  }
  __syncthreads();

  // ---- epilogue: thread t owns one point; full-wave 256B-contiguous stores ----
  const int np = blockIdx.x * PTS + t;
  const int kwin = klds[t];
  const float4* er = reinterpret_cast<const float4*>(emb + (kwin << 6));
  #pragma unroll
  for (int jj = 0; jj < 16; ++jj) {
    float4 v = er[jj];
    out[(size_t)(4 * jj + 0) * Npts + np] = v.x;
    out[(size_t)(4 * jj + 1) * Npts + np] = v.y;
    out[(size_t)(4 * jj + 2) * Npts + np] = v.z;
    out[(size_t)(4 * jj + 3) * Npts + np] = v.w;
  }
}

// ---------- fallback: exact arithmetic for risky points (1 wave/point, 4096 waves) ----------
__global__ __launch_bounds__(256) void vq_fix(
    const float* __restrict__ ze, const float* __restrict__ emb,
    const float* __restrict__ en, float* __restrict__ out,
    const unsigned int* __restrict__ cnt, const unsigned int* __restrict__ list,
    unsigned int listcap) {
  const int t = threadIdx.x;
  const int wave = t >> 6, lane = t & 63;
  unsigned count = *cnt;
  if (count > listcap) count = listcap;
  const unsigned wid = blockIdx.x * 4 + wave;
  for (unsigned i = wid; i < count; i += 4096) {
    const int n = (int)list[i];
    const int b = n >> 12, hw = n & (HWs - 1);
    const float* xp = ze + (size_t)b * (Cdim * HWs) + hw;
    float x[Cdim];
    #pragma unroll
    for (int c = 0; c < Cdim; ++c) x[c] = xp[c * HWs];
    float xn0 = 0.f, xn1 = 0.f, xn2 = 0.f, xn3 = 0.f;
    #pragma unroll
    for (int c = 0; c < Cdim; c += 4) {
      xn0 = fmaf(x[c], x[c], xn0);         xn1 = fmaf(x[c + 1], x[c + 1], xn1);
      xn2 = fmaf(x[c + 2], x[c + 2], xn2); xn3 = fmaf(x[c + 3], x[c + 3], xn3);
    }
    const float xnorm = (xn0 + xn1) + (xn2 + xn3);
    float best = 3.4e38f; int bestk = 0;
    for (int kk = 0; kk < 16; ++kk) {
      const int k = kk * 64 + lane;    // ascending within lane; coalesced en/emb reads
      const float4* er2 = reinterpret_cast<const float4*>(emb + (k << 6));
      float d0 = 0.f, d1 = 0.f, d2 = 0.f, d3 = 0.f;
      #pragma unroll
      for (int j = 0; j < 16; ++j) {
        float4 v = er2[j];
        d0 = fmaf(x[4 * j + 0], v.x, d0); d1 = fmaf(x[4 * j + 1], v.y, d1);
        d2 = fmaf(x[4 * j + 2], v.z, d2); d3 = fmaf(x[4 * j + 3], v.w, d3);
      }
      const float dot = (d0 + d1) + (d2 + d3);
      const float tt = xnorm + en[k];
      const float d = __fsub_rn(tt, __fmul_rn(2.0f, dot));
      if (d < best) { best = d; bestk = k; }
    }
    // lexicographic (d, k) wave reduce == global ascending-k first-min
    #pragma unroll
    for (int m = 1; m < 64; m <<= 1) {
      const float od = __shfl_xor(best, m, 64);
      const int   ok = __shfl_xor(bestk, m, 64);
      const bool take = (od < best) || (od == best && ok < bestk);
      best = take ? od : best;
      bestk = take ? ok : bestk;
    }
    out[(size_t)lane * Npts + n] = emb[(bestk << 6) + lane];
  }
}

// ---------- safety net (ws too small): round-4 proven kernel ----------
__global__ __launch_bounds__(256) void vq_direct(
    const float* __restrict__ ze, const float* __restrict__ emb, float* __restrict__ out) {
  __shared__ float en_s[Kcb];
  __shared__ float bestd_s[4][64];
  __shared__ int   bestk_s[4][64];
  const int t = threadIdx.x, wave = t >> 6, lane = t & 63;
  #pragma unroll
  for (int r = 0; r < 4; ++r) {
    const int k = t + r * 256;
    const float4* row = reinterpret_cast<const float4*>(emb + (k << 6));
    float a0 = 0.f, a1 = 0.f, a2 = 0.f, a3 = 0.f;
    #pragma unroll
    for (int j = 0; j < 16; ++j) {
      float4 v = row[j];
      a0 = fmaf(v.x, v.x, a0); a1 = fmaf(v.y, v.y, a1);
      a2 = fmaf(v.z, v.z, a2); a3 = fmaf(v.w, v.w, a3);
    }
    en_s[k] = (a0 + a1) + (a2 + a3);
  }
  __syncthreads();
  const int n = blockIdx.x * 64 + lane;
  const int b = n >> 12, hw = n & (HWs - 1);
  const float* xp = ze + (b * Cdim) * HWs + hw;
  float x[Cdim];
  #pragma unroll
  for (int c = 0; c < Cdim; ++c) x[c] = xp[c * HWs];
  float xn0 = 0.f, xn1 = 0.f, xn2 = 0.f, xn3 = 0.f;
  #pragma unroll
  for (int c = 0; c < Cdim; c += 4) {
    xn0 = fmaf(x[c], x[c], xn0); xn1 = fmaf(x[c + 1], x[c + 1], xn1);
    xn2 = fmaf(x[c + 2], x[c + 2], xn2); xn3 = fmaf(x[c + 3], x[c + 3], xn3);
  }
  const float xnorm = (xn0 + xn1) + (xn2 + xn3);
  const int wu = __builtin_amdgcn_readfirstlane(wave);
  const int kbase = wu * 256;
  float best = 3.4e38f; int bestk = 0;
  #pragma unroll 2
  for (int kk = 0; kk < 256; ++kk) {
    const int k = kbase + kk;
    const float4* er = reinterpret_cast<const float4*>(emb + (k << 6));
    float d0 = 0.f, d1 = 0.f, d2 = 0.f, d3 = 0.f;
    #pragma unroll
    for (int j = 0; j < 16; ++j) {
      float4 v = er[j];
      d0 = fmaf(x[4 * j + 0], v.x, d0); d1 = fmaf(x[4 * j + 1], v.y, d1);
      d2 = fmaf(x[4 * j + 2], v.z, d2); d3 = fmaf(x[4 * j + 3], v.w, d3);
    }
    const float dot = (d0 + d1) + (d2 + d3);
    const float tt = xnorm + en_s[k];
    const float d = __fsub_rn(tt, __fmul_rn(2.0f, dot));
    if (d < best) { best = d; bestk = k; }
  }
  bestd_s[wave][lane] = best; bestk_s[wave][lane] = bestk;
  __syncthreads();
  float bdv = bestd_s[0][lane]; int bkv = bestk_s[0][lane];
  #pragma unroll
  for (int w = 1; w < 4; ++w) {
    const float dw = bestd_s[w][lane]; const int kw = bestk_s[w][lane];
    if (dw < bdv) { bdv = dw; bkv = kw; }
  }
  const int np = blockIdx.x * 64 + lane;
  const int c0 = wave * 16;
  const float4* brow = reinterpret_cast<const float4*>(emb + (bkv << 6) + c0);
  #pragma unroll
  for (int j = 0; j < 4; ++j) {
    float4 v = brow[j];
    out[(c0 + 4 * j + 0) * Npts + np] = v.x;
    out[(c0 + 4 * j + 1) * Npts + np] = v.y;
    out[(c0 + 4 * j + 2) * Npts + np] = v.z;
    out[(c0 + 4 * j + 3) * Npts + np] = v.w;
  }
}

extern "C" void kernel_launch(void* const* d_in, const int* in_sizes, int n_in,
                              void* d_out, int out_size, void* d_ws, size_t ws_size,
                              hipStream_t stream) {
  (void)in_sizes; (void)n_in; (void)out_size;
  const float* ze  = (const float*)d_in[0];
  const float* emb = (const float*)d_in[1];
  float* out = (float*)d_out;

  if (ws_size < WS_NEED) {   // safety net: proven round-4 path
    vq_direct<<<Npts / 64, 256, 0, stream>>>(ze, emb, out);
    return;
  }
  unsigned char* ws = (unsigned char*)d_ws;
  unsigned short* eh = (unsigned short*)(ws + WS_EH);
  unsigned short* el = (unsigned short*)(ws + WS_EL);
  float* en          = (float*)(ws + WS_EN);
  unsigned* cnt      = (unsigned*)(ws + WS_CNT);
  unsigned* list     = (unsigned*)(ws + WS_LIST);

  hipMemsetAsync(cnt, 0, 4, stream);
  vq_prep<<<Kcb / 256, 256, 0, stream>>>(emb, eh, el, en);
  vq_main<<<Npts / PTS, 256, 0, stream>>>(ze, emb, eh, el, en, out, cnt, list, (unsigned)Npts);
  vq_fix<<<1024, 256, 0, stream>>>(ze, emb, en, out, cnt, list, (unsigned)Npts);
}